// Round 14
// baseline (200.364 us; speedup 1.0000x reference)
//
#include <hip/hip_runtime.h>
#include <hip/hip_bf16.h>

typedef unsigned short ushort_t;
typedef __attribute__((ext_vector_type(8))) short s8v;   // 8 bf16 = 4 VGPR (MFMA A/B frag)
typedef __attribute__((ext_vector_type(4))) float f4;    // 4 fp32 acc (MFMA C/D frag)
typedef __attribute__((ext_vector_type(4))) unsigned short u16x4;

// Problem constants: B=2, T=2048, M=512, C=512, H=8, D=64
#define BB 2
#define TT 2048
#define MMM 512
#define CC 512
#define HH 8
#define DD 64
#define SCALE 0.125f
// SCALE * log2(e): folded into q_x so softmax uses bare v_exp_f32 (2^x)
#define SCALE_L2E 0.18033688011112042f

__device__ __forceinline__ ushort_t f2bf(float v) {
    __hip_bfloat16 h = __float2bfloat16(v);
    return *reinterpret_cast<ushort_t*>(&h);
}
__device__ __forceinline__ float bf2f(ushort_t u) {
    __hip_bfloat16 h;
    *reinterpret_cast<ushort_t*>(&h) = u;
    return __bfloat162float(h);
}
// bare 2^x (v_exp_f32). Inputs pre-scaled by log2(e).
__device__ __forceinline__ float exp2_raw(float v) {
    float p;
    asm("v_exp_f32 %0, %1" : "=v"(p) : "v"(v));
    return p;
}

// async global->LDS, 16B per lane. LDS dst = wave-uniform base + lane*16.
__device__ __forceinline__ void gload16(const void* g, void* l) {
    __builtin_amdgcn_global_load_lds((const __attribute__((address_space(1))) void*)g,
                                     (__attribute__((address_space(3))) void*)l, 16, 0, 0);
}

// ---------------------------------------------------------------------------
// prep_k: x/y fp32->bf16 (float4-vectorized) + 5 weight transposes
// (one-pass vectorized, R25).
// ---------------------------------------------------------------------------
__device__ __forceinline__ void transp32(const float* W, ushort_t* WT, int K, int N,
                                         int bx, int by, int tid) {
    const int k0 = by * 32, n0 = bx * 32;
    __shared__ float t[32][33];
    {
        int r = tid >> 3, c = (tid & 7) * 4;
        float4 v = *(const float4*)&W[(long)(k0 + r) * N + n0 + c];
        t[r][c] = v.x; t[r][c + 1] = v.y; t[r][c + 2] = v.z; t[r][c + 3] = v.w;
    }
    __syncthreads();
    {
        int n = tid >> 3, k = (tid & 7) * 4;
        u16x4 o;
        o[0] = f2bf(t[k][n]);     o[1] = f2bf(t[k + 1][n]);
        o[2] = f2bf(t[k + 2][n]); o[3] = f2bf(t[k + 3][n]);
        *(u16x4*)&WT[(long)(n0 + n) * K + k0 + k] = o;
    }
}
__device__ __forceinline__ void cvt4(const float* s, ushort_t* d, long blk, int tid) {
    long i = (blk * 256 + tid) * 4;
    float4 v = *(const float4*)(s + i);
    u16x4 o;
    o[0] = f2bf(v.x); o[1] = f2bf(v.y); o[2] = f2bf(v.z); o[3] = f2bf(v.w);
    *(u16x4*)(d + i) = o;
}

__global__ __launch_bounds__(256) void prep_k(
    const float* __restrict__ x, const float* __restrict__ y,
    const float* __restrict__ Wqx, const float* __restrict__ Wqy,
    const float* __restrict__ Wgs, const float* __restrict__ Wgc,
    const float* __restrict__ Wp,
    ushort_t* __restrict__ xb, ushort_t* __restrict__ yb,
    ushort_t* __restrict__ WqxT, ushort_t* __restrict__ WqyT,
    ushort_t* __restrict__ WgsT, ushort_t* __restrict__ WgcT,
    ushort_t* __restrict__ WpT)
{
    const int bid = blockIdx.x, tid = threadIdx.x;
    if (bid < 2048)      cvt4(x, xb, bid, tid);
    else if (bid < 2560) cvt4(y, yb, bid - 2048, tid);
    else if (bid < 3328) { int l = bid - 2560; transp32(Wqx, WqxT, 512, 1536, l % 48, l / 48, tid); }
    else if (bid < 4096) { int l = bid - 3328; transp32(Wqy, WqyT, 512, 1536, l % 48, l / 48, tid); }
    else if (bid < 4352) { int l = bid - 4096; transp32(Wgs, WgsT, 512, 512, l % 16, l / 16, tid); }
    else if (bid < 4608) { int l = bid - 4352; transp32(Wgc, WgcT, 512, 512, l % 16, l / 16, tid); }
    else                 { int l = bid - 4608; transp32(Wp, WpT, 512, 512, l % 16, l / 16, tid); }
}

// ---------------------------------------------------------------------------
// staging helpers (XOR-swizzled LDS layout, 16B/lane global_load_lds)
// ---------------------------------------------------------------------------
__device__ __forceinline__ void stage_rows64(const ushort_t* src, long k0,
                                             ushort_t* dstL, int w, int lane) {
#pragma unroll
    for (int n = 0; n < 2; ++n) {
        int f = w * 2048 + n * 1024 + lane * 16;
        int row = f >> 7;
        int blk_g = ((f & 127) >> 4) ^ (row & 7);
        gload16(src + (long)row * 512 + k0 + blk_g * 8, dstL + ((w * 2048 + n * 1024) >> 1));
    }
}
// 128-row tile staged by 8 waves (512-thread blocks): 2 gloads/wave.
__device__ __forceinline__ void stage_rows128_8w(const ushort_t* src, long k0,
                                                 ushort_t* dstL, int w, int lane) {
#pragma unroll
    for (int n = 0; n < 2; ++n) {
        int f = w * 2048 + n * 1024 + lane * 16;
        int row = f >> 7;
        int blk_g = ((f & 127) >> 4) ^ (row & 7);
        gload16(src + (long)row * 512 + k0 + blk_g * 8, dstL + ((w * 2048 + n * 1024) >> 1));
    }
}

// ---------------------------------------------------------------------------
// Combined QKV NT GEMM + fused transpose epilogue.
// R26: 512-THREAD BLOCKS — same 128x128 tile & 64KB dbuf -> still 2 blocks/CU
// but 16 waves/CU (was 8): while one block's waves sit in the barrier's
// vmcnt-drain, the co-resident block now has 8 (vs 4) waves issuing (m114
// implicit overlap, doubled fill). Per-wave: acc[2][4], 2 gloads/array/step.
// ---------------------------------------------------------------------------
__global__ __launch_bounds__(512) void qkv_k(
    const ushort_t* __restrict__ xb, const ushort_t* __restrict__ yb,
    const ushort_t* __restrict__ WqxT, const ushort_t* __restrict__ WqyT,
    const float* __restrict__ bqx, const float* __restrict__ bqy,
    ushort_t* __restrict__ qkvx, ushort_t* __restrict__ qkvy,
    ushort_t* __restrict__ vxT, ushort_t* __restrict__ vyT,
    ushort_t* __restrict__ kyT, ushort_t* __restrict__ qyT)
{
    const int by = blockIdx.y;
    const ushort_t* A; const ushort_t* Bm; const float* bias; ushort_t* O;
    int r0, qcols;
    if (by < 32) { A = xb; Bm = WqxT; bias = bqx; O = qkvx; r0 = by * 128; qcols = 512; }
    else         { A = yb; Bm = WqyT; bias = bqy; O = qkvy; r0 = (by - 32) * 128; qcols = 0; }
    const int c0 = blockIdx.x * 128;
    const int tid = threadIdx.x, w = tid >> 6, lane = tid & 63;
    const int quad = lane >> 4, l15 = lane & 15;
    const int rowBase = (w >> 1) * 32, colBase = (w & 1) * 64;   // 8 waves: 32x64 each

    // pool: [0,8192)=A0 [8192,16384)=A1 [16384,24576)=B0 [24576,32768)=B1
    // (ushorts); epilogue transpose scratch t[128][136]=17408 aliases [0,..).
    __shared__ __align__(16) ushort_t sh[32768];

    const ushort_t* Ab = A + (long)r0 * 512;
    const ushort_t* Bb = Bm + (long)c0 * 512;

    f4 acc[2][4] = {};

    stage_rows128_8w(Ab, 0, sh, w, lane);
    stage_rows128_8w(Bb, 0, sh + 16384, w, lane);
    __syncthreads();

    for (int kk = 0; kk < 8; ++kk) {
        const int cur = kk & 1;
        ushort_t* AlCur = sh + cur * 8192;
        ushort_t* BlCur = sh + 16384 + cur * 8192;
        if (kk < 7) {
            stage_rows128_8w(Ab, (kk + 1) * 64, sh + (cur ^ 1) * 8192, w, lane);
            stage_rows128_8w(Bb, (kk + 1) * 64, sh + 16384 + (cur ^ 1) * 8192, w, lane);
        }
#pragma unroll
        for (int ks = 0; ks < 2; ++ks) {
            s8v af[2], bfr[4];
#pragma unroll
            for (int i = 0; i < 2; ++i) {
                int row = rowBase + 16 * i + l15;
                af[i] = *(const s8v*)&AlCur[row * 64 + (((ks * 4 + quad) ^ (row & 7)) * 8)];
            }
#pragma unroll
            for (int j = 0; j < 4; ++j) {
                int col = colBase + 16 * j + l15;
                bfr[j] = *(const s8v*)&BlCur[col * 64 + (((ks * 4 + quad) ^ (col & 7)) * 8)];
            }
#pragma unroll
            for (int i = 0; i < 2; ++i)
#pragma unroll
                for (int j = 0; j < 4; ++j)
                    acc[i][j] = __builtin_amdgcn_mfma_f32_16x16x32_bf16(af[i], bfr[j], acc[i][j], 0, 0, 0);
        }
        __syncthreads();
    }

    // transpose destination select (block-uniform)
    ushort_t* dstT = nullptr; long zb = 0; int S = 0, srow0 = 0, h0 = 0;
    if (by < 32) {
        if (c0 >= 1024) {
            dstT = vxT; S = TT; zb = (long)(r0 >> 11) * 8;
            h0 = (c0 - 1024) >> 6; srow0 = r0 & 2047;
        }
    } else {
        const int slice = c0 >> 9;   // 0:q 1:k 2:v of y
        dstT = (slice == 0) ? qyT : (slice == 1) ? kyT : vyT;
        S = MMM; zb = (long)(r0 >> 9) * 8;
        h0 = (c0 & 511) >> 6; srow0 = r0 & 511;
    }

    // epilogue: normal O write + (optional) LDS scratch write for transpose
#pragma unroll
    for (int i = 0; i < 2; ++i)
#pragma unroll
        for (int j = 0; j < 4; ++j)
#pragma unroll
            for (int r = 0; r < 4; ++r) {
                int lrow = rowBase + 16 * i + quad * 4 + r;
                int lcol = colBase + 16 * j + l15;
                int col = c0 + lcol;
                float v = acc[i][j][r] + bias[col];
                if (col < qcols) v *= SCALE_L2E;   // fold SCALE*log2e into q_x
                ushort_t bv = f2bf(v);
                O[(long)(r0 + lrow) * 1536 + col] = bv;
                if (dstT) sh[lrow * 136 + (lcol ^ (((lrow >> 3) & 7) * 8))] = bv;
            }

    if (dstT) {
        __syncthreads();
        // 2048 tasks: (d128, s-chunk). 16 consecutive threads share d128 ->
        // 16 x 16B contiguous global stores (coalesced 256B).
#pragma unroll
        for (int p = 0; p < 4; ++p) {
            int task = p * 512 + tid;
            int d128 = task >> 4, sc = task & 15;
            s8v o;
#pragma unroll
            for (int k = 0; k < 8; ++k)
                o[k] = (short)sh[(sc * 8 + k) * 136 + (d128 ^ ((sc & 7) * 8))];
            int h = h0 + (d128 >> 6), d = d128 & 63;
            long addr = ((zb + h) * 64 + d) * (long)S + srow0 + sc * 8;
            *(s8v*)&dstT[addr] = o;
        }
    }
}

// ---------------------------------------------------------------------------
// Proj NT GEMM. 64x64 tile (grid 8x64 = 512 blocks -> 2 blocks/CU),
// 3-slot ring + counted vmcnt single-barrier pipeline.
// ---------------------------------------------------------------------------
__global__ __launch_bounds__(256) void proj_k(
    const ushort_t* __restrict__ A, const ushort_t* __restrict__ Bm,
    float* __restrict__ O, const float* __restrict__ bias)
{
    const int r0 = blockIdx.y * 64, c0 = blockIdx.x * 64;
    const int tid = threadIdx.x, w = tid >> 6, lane = tid & 63;
    const int quad = lane >> 4, l15 = lane & 15;
    const int rowBase = (w >> 1) * 32, colBase = (w & 1) * 32;

    __shared__ __align__(16) ushort_t Al[3][64 * 64];
    __shared__ __align__(16) ushort_t Bl[3][64 * 64];

    const ushort_t* Ab = A + (long)r0 * 512;
    const ushort_t* Bb = Bm + (long)c0 * 512;

    f4 acc[2][2] = {};

    stage_rows64(Ab, 0, Al[0], w, lane);
    stage_rows64(Bb, 0, Bl[0], w, lane);
    stage_rows64(Ab, 64, Al[1], w, lane);
    stage_rows64(Bb, 64, Bl[1], w, lane);

    int cur = 0;
    for (int kk = 0; kk < 8; ++kk) {
        if (kk + 1 < 8) asm volatile("s_waitcnt vmcnt(4)" ::: "memory");
        else            asm volatile("s_waitcnt vmcnt(0)" ::: "memory");
        asm volatile("s_barrier" ::: "memory");
        if (kk + 2 < 8) {
            int s = cur + 2; if (s >= 3) s -= 3;
            stage_rows64(Ab, (kk + 2) * 64, Al[s], w, lane);
            stage_rows64(Bb, (kk + 2) * 64, Bl[s], w, lane);
        }
#pragma unroll
        for (int ks = 0; ks < 2; ++ks) {
            s8v af[2], bfr[2];
#pragma unroll
            for (int i = 0; i < 2; ++i) {
                int row = rowBase + 16 * i + l15;
                af[i] = *(const s8v*)&Al[cur][row * 64 + (((ks * 4 + quad) ^ (row & 7)) * 8)];
                int col = colBase + 16 * i + l15;
                bfr[i] = *(const s8v*)&Bl[cur][col * 64 + (((ks * 4 + quad) ^ (col & 7)) * 8)];
            }
#pragma unroll
            for (int i = 0; i < 2; ++i)
#pragma unroll
                for (int j = 0; j < 2; ++j)
                    acc[i][j] = __builtin_amdgcn_mfma_f32_16x16x32_bf16(af[i], bfr[j], acc[i][j], 0, 0, 0);
        }
        if (++cur == 3) cur = 0;
    }

#pragma unroll
    for (int i = 0; i < 2; ++i)
#pragma unroll
        for (int j = 0; j < 2; ++j)
#pragma unroll
            for (int r = 0; r < 4; ++r) {
                int row = r0 + rowBase + 16 * i + quad * 4 + r;
                int col = c0 + colBase + 16 * j + l15;
                O[(long)row * 512 + col] = acc[i][j][r] + bias[col];
            }
}

// ---------------------------------------------------------------------------
// Gt[z][d2][d1] = SCALE^2 * sum_m q_y[m,d2]*k_y[m,d1]  (8-wave split-M, R25).
// ---------------------------------------------------------------------------
__global__ __launch_bounds__(512) void gt_k(const ushort_t* __restrict__ qyT,
                                            const ushort_t* __restrict__ kyT,
                                            ushort_t* __restrict__ Gt)
{
    const int z = blockIdx.x;
    const int tid = threadIdx.x, w = tid >> 6, lane = tid & 63;
    const int quad = lane >> 4, l15 = lane & 15;
    const ushort_t* A  = qyT + (long)z * 64 * MMM;
    const ushort_t* Bm = kyT + (long)z * 64 * MMM;
    __shared__ float red[8][4096];
    f4 acc[4][4] = {};
#pragma unroll
    for (int kk = 0; kk < 2; ++kk) {
        const int ks = w * 2 + kk;
        s8v af[4], bfr[4];
#pragma unroll
        for (int i = 0; i < 4; ++i) {
            af[i]  = *(const s8v*)(A  + (long)(16 * i + l15) * MMM + ks * 32 + quad * 8);
            bfr[i] = *(const s8v*)(Bm + (long)(16 * i + l15) * MMM + ks * 32 + quad * 8);
        }
#pragma unroll
        for (int i = 0; i < 4; ++i)
#pragma unroll
            for (int j = 0; j < 4; ++j)
                acc[i][j] = __builtin_amdgcn_mfma_f32_16x16x32_bf16(af[i], bfr[j], acc[i][j], 0, 0, 0);
    }
#pragma unroll
    for (int i = 0; i < 4; ++i)
#pragma unroll
        for (int j = 0; j < 4; ++j)
            *(f4*)&red[w][(i * 4 + j) * 256 + lane * 4] = acc[i][j];
    __syncthreads();
    const float s2 = SCALE * SCALE;
    const int iw = w & 3, j0 = (w >> 2) * 2;
#pragma unroll
    for (int jj = 0; jj < 2; ++jj) {
        const int j = j0 + jj;
        f4 s = *(const f4*)&red[0][(iw * 4 + j) * 256 + lane * 4];
#pragma unroll
        for (int ww = 1; ww < 8; ++ww)
            s += *(const f4*)&red[ww][(iw * 4 + j) * 256 + lane * 4];
#pragma unroll
        for (int r = 0; r < 4; ++r) {
            int d2 = 16 * iw + quad * 4 + r, d1 = 16 * j + l15;
            Gt[(long)z * 4096 + d2 * 64 + d1] = f2bf(s2 * s[r]);
        }
    }
}

// ---------------------------------------------------------------------------
// Fused 3-stream flash — R7/R10 config (measured best: 58.3-59.9us, passing).
// ---------------------------------------------------------------------------
__device__ __forceinline__ void stage_k64(const ushort_t* src, long rstride, int s0,
                                          ushort_t* Kl, int w, int lane) {
#pragma unroll
    for (int n = 0; n < 2; ++n) {
        int f = w * 2048 + n * 1024 + lane * 16;
        int row = f >> 7;
        int krow = ((row & 15) << 2) | (row >> 4);   // k-interleave permutation
        int blk = ((f & 127) >> 4) ^ (row & 7);
        gload16(src + (long)(s0 + krow) * rstride + blk * 8, &Kl[(w * 2048 + n * 1024) >> 1]);
    }
}
__device__ __forceinline__ void stage_v64(const ushort_t* src, long rstride, int s0,
                                          ushort_t* Vl, int w, int lane) {
#pragma unroll
    for (int n = 0; n < 2; ++n) {
        int f = w * 2048 + n * 1024 + lane * 16;
        int row = f >> 7;
        int blk = ((f & 127) >> 4) ^ (row & 7);
        gload16(src + (long)row * rstride + s0 + blk * 8, &Vl[(w * 2048 + n * 1024) >> 1]);
    }
}
__device__ __forceinline__ void qk8(f4 Sc[4], const s8v qf[2], const ushort_t* Kl,
                                    int quad, int l15) {
    __builtin_amdgcn_s_setprio(1);
#pragma unroll
    for (int ks = 0; ks < 2; ++ks)
#pragma unroll
        for (int c = 0; c < 4; ++c) {
            int row = 16 * c + l15;
            s8v bb = *(const s8v*)&Kl[row * 64 + (((ks * 4 + quad) ^ (row & 7)) * 8)];
            Sc[c] = __builtin_amdgcn_mfma_f32_16x16x32_bf16(qf[ks], bb, Sc[c], 0, 0, 0);
        }
    __builtin_amdgcn_s_setprio(0);
}
__device__ __forceinline__ void qk8_dual(f4 Ss[4], f4 Sp[4], const s8v qa[2], const s8v qb[2],
                                         const ushort_t* Kl, int quad, int l15) {
    __builtin_amdgcn_s_setprio(1);
#pragma unroll
    for (int ks = 0; ks < 2; ++ks)
#pragma unroll
        for (int c = 0; c < 4; ++c) {
            int row = 16 * c + l15;
            s8v bb = *(const s8v*)&Kl[row * 64 + (((ks * 4 + quad) ^ (row & 7)) * 8)];
            Ss[c] = __builtin_amdgcn_mfma_f32_16x16x32_bf16(qa[ks], bb, Ss[c], 0, 0, 0);
            Sp[c] = __builtin_amdgcn_mfma_f32_16x16x32_bf16(qb[ks], bb, Sp[c], 0, 0, 0);
        }
    __builtin_amdgcn_s_setprio(0);
}
// preload the 8 V fragments of this tile into registers (issued before smax
// so the ds_read latency overlaps the softmax VALU chain)
__device__ __forceinline__ void vload8(s8v vf[8], const ushort_t* Vl, int quad, int l15) {
#pragma unroll
    for (int ks = 0; ks < 2; ++ks)
#pragma unroll
        for (int c = 0; c < 4; ++c) {
            int row = 16 * c + l15;
            vf[ks * 4 + c] = *(const s8v*)&Vl[row * 64 + (((ks * 4 + quad) ^ (row & 7)) * 8)];
        }
}
// fixed-max softmax: p = 2^v (logits pre-scaled by log2e); lane-local l;
// P written as packed b64 (k-cols 4*l15..4*l15+3 consecutive after interleave)
__device__ __forceinline__ void smax0(const f4 Sc[4], float l_i[4], ushort_t* PlW,
                                      int diag, int trow0, int s0, int quad, int l15) {
#pragma unroll
    for (int r = 0; r < 4; ++r) {
        const int trow = trow0 + quad * 4 + r;
        u16x4 o;
#pragma unroll
        for (int c = 0; c < 4; ++c) {
            float v = Sc[c][r];
            if (diag && (s0 + 4 * l15 + c) > trow) v = -3e38f;
            float p = exp2_raw(v);
            l_i[r] += p;
            o[c] = f2bf(p);
        }
        *(u16x4*)&PlW[(quad * 4 + r) * 72 + 4 * l15] = o;
    }
}
// PV consuming register V-frags (P still via per-wave LDS)
__device__ __forceinline__ void pv8r(f4 Oc[4], const ushort_t* PlW, const s8v vf[8],
                                     int quad, int l15) {
    __builtin_amdgcn_s_setprio(1);
#pragma unroll
    for (int ks = 0; ks < 2; ++ks) {
        s8v a = *(const s8v*)&PlW[l15 * 72 + ks * 32 + quad * 8];
#pragma unroll
        for (int c = 0; c < 4; ++c)
            Oc[c] = __builtin_amdgcn_mfma_f32_16x16x32_bf16(a, vf[ks * 4 + c], Oc[c], 0, 0, 0);
    }
    __builtin_amdgcn_s_setprio(0);
}
__device__ __forceinline__ void pv8r_dual(f4 Os[4], f4 Op[4], const ushort_t* Ps,
                                          const ushort_t* Pp, const s8v vf[8],
                                          int quad, int l15) {
    __builtin_amdgcn_s_setprio(1);
#pragma unroll
    for (int ks = 0; ks < 2; ++ks) {
        s8v as = *(const s8v*)&Ps[l15 * 72 + ks * 32 + quad * 8];
        s8v ap = *(const s8v*)&Pp[l15 * 72 + ks * 32 + quad * 8];
#pragma unroll
        for (int c = 0; c < 4; ++c) {
            Os[c] = __builtin_amdgcn_mfma_f32_16x16x32_bf16(as, vf[ks * 4 + c], Os[c], 0, 0, 0);
            Op[c] = __builtin_amdgcn_mfma_f32_16x16x32_bf16(ap, vf[ks * 4 + c], Op[c], 0, 0, 0);
        }
    }
    __builtin_amdgcn_s_setprio(0);
}

__global__ __launch_bounds__(256, 2) void flash_fused(
    const ushort_t* __restrict__ qkvx, const ushort_t* __restrict__ qkvy,
    const ushort_t* __restrict__ Gt, const ushort_t* __restrict__ vxT,
    const ushort_t* __restrict__ vyT,
    ushort_t* __restrict__ cval, ushort_t* __restrict__ sval)
{
    const int z = blockIdx.y, b = z >> 3, h = z & 7;
    const ushort_t* qx = qkvx + (long)b * (TT * 1536) + h * 64;   // pre-scaled SCALE*log2e
    const ushort_t* kx = qx + 512;
    const ushort_t* ky = qkvy + (long)b * (MMM * 1536) + 512 + h * 64;
    const ushort_t* Gz = Gt + (long)z * 4096;
    const ushort_t* vx = vxT + (long)z * (64 * TT);
    const ushort_t* vy = vyT + (long)z * (64 * MMM);

    // load-balance: z<8 long-first, z>=8 short-first (R2's best-measured pairing)
    const int xw = (z & 8) ? (int)blockIdx.x : (int)(gridDim.x - 1 - blockIdx.x);
    const int t0 = xw * 64;
    const int tid = threadIdx.x, w = tid >> 6, lane = tid & 63;
    const int quad = lane >> 4, l15 = lane & 15;

    __shared__ __align__(16) ushort_t Kl[2][64 * 64];
    __shared__ __align__(16) ushort_t Vl[2][64 * 64];
    __shared__ __align__(16) ushort_t Pl[2][4 * 16 * 72];   // [stream][wave P]
    ushort_t* PlWs = &Pl[0][w * 1152];
    ushort_t* PlWp = &Pl[1][w * 1152];

    // prefetch tile 0 (cross) early
    stage_k64(ky, 1536, 0, Kl[0], w, lane);
    stage_v64(vy, MMM, 0, Vl[0], w, lane);

    // Q frags + q~ = qx_scaled @ Gt^T (permuted Gt rows -> packed P writes).
    const int qrow = t0 + 16 * w + l15;
    s8v qfx[2], qft[2];
    qfx[0] = *(const s8v*)(qx + (long)qrow * 1536 + quad * 8);
    qfx[1] = *(const s8v*)(qx + (long)qrow * 1536 + 32 + quad * 8);
    {
        f4 qa[4] = {};
#pragma unroll
        for (int ks = 0; ks < 2; ++ks)
#pragma unroll
            for (int j = 0; j < 4; ++j) {
                s8v bb = *(const s8v*)(Gz + (4 * l15 + j) * 64 + ks * 32 + quad * 8);
                qa[j] = __builtin_amdgcn_mfma_f32_16x16x32_bf16(qfx[ks], bb, qa[j], 0, 0, 0);
            }
#pragma unroll
        for (int r = 0; r < 4; ++r) {
            u16x4 o;
#pragma unroll
            for (int j = 0; j < 4; ++j) o[j] = f2bf(qa[j][r]);
            *(u16x4*)&PlWs[(quad * 4 + r) * 72 + 4 * l15] = o;
        }
        qft[0] = *(const s8v*)&PlWs[l15 * 72 + quad * 8];
        qft[1] = *(const s8v*)&PlWs[l15 * 72 + 32 + quad * 8];
    }

    f4 Occ[4] = {}, Ocs[4] = {}, Ocp[4] = {};
    float lc[4] = {}, ls[4] = {}, lp[4] = {};

    const int nT1 = MMM / 64;                 // 8 cross tiles
    const int nTiles = nT1 + t0 / 64 + 1;

    for (int ti = 0; ti < nTiles; ++ti) {
        const int bi = ti & 1;
        __syncthreads();   // drains cur-buf loads
        if (ti + 1 < nTiles) {
            const int tn = ti + 1, bn = tn & 1;
            if (tn < nT1) {
                stage_k64(ky, 1536, tn * 64, Kl[bn], w, lane);
                stage_v64(vy, MMM, tn * 64, Vl[bn], w, lane);
            } else {
                const int s0n = (tn - nT1) * 64;
                stage_k64(kx, 1536, s0n, Kl[bn], w, lane);
                stage_v64(vx, TT, s0n, Vl[bn], w, lane);
            }
        }
        if (ti < nT1) {
            // ---- cross: qk -> vload (overlaps smax) -> smax -> pv(regs) ----
            f4 Sc[4] = {};
            qk8(Sc, qfx, Kl[bi], quad, l15);
            s8v vf[8];
            vload8(vf, Vl[bi], quad, l15);
            smax0(Sc, lc, PlWs, 0, 0, 0, quad, l15);
            pv8r(Occ, PlWs, vf, quad, l15);
        } else {
            // ---- causal: dual-stream with shared K/V frags ----
            const int s0 = (ti - nT1) * 64;
            const int diag = (s0 == t0);
            f4 Ss[4] = {}, Sp[4] = {};
            qk8_dual(Ss, Sp, qfx, qft, Kl[bi], quad, l15);
            s8v vf[8];
            vload8(vf, Vl[bi], quad, l15);
            smax0(Ss, ls, PlWs, diag, t0 + 16 * w, s0, quad, l15);
            smax0(Sp, lp, PlWp, diag, t0 + 16 * w, s0, quad, l15);
            pv8r_dual(Ocs, Ocp, PlWs, PlWp, vf, quad, l15);
        }
    }

    // reduce l over the 16 lanes of each quad-group (cols of the row)
#pragma unroll
    for (int r = 0; r < 4; ++r)
#pragma unroll
        for (int mb = 1; mb < 16; mb <<= 1) {
            lc[r] += __shfl_xor(lc[r], mb, 64);
            ls[r] += __shfl_xor(ls[r], mb, 64);
            lp[r] += __shfl_xor(lp[r], mb, 64);
        }

    const long ob = (long)b * (TT * CC) + h * 64;
#pragma unroll
    for (int r = 0; r < 4; ++r) {
        int row = t0 + 16 * w + quad * 4 + r;
        float ic = 1.f / lc[r], ip = 1.f / lp[r], isv = 1.f / ls[r];
#pragma unroll
        for (int c = 0; c < 4; ++c) {
            long idx = ob + (long)row * CC + 16 * c + l15;
            cval[idx] = f2bf(Occ[c][r] * ic + Ocp[c][r] * ip);
            sval[idx] = f2bf(Ocs[c][r] * isv);
        }
    }
}

// ---------------------------------------------------------------------------
// Fused gate: SINGLE pass over K — both gate GEMMs per k-step (R10, −4us).
// ---------------------------------------------------------------------------
__global__ __launch_bounds__(256) void gate_gemm(
    const ushort_t* __restrict__ sval, const ushort_t* __restrict__ cvalb,
    const ushort_t* __restrict__ WgsT, const ushort_t* __restrict__ WgcT,
    const float* __restrict__ bgs, const float* __restrict__ bgc,
    ushort_t* __restrict__ tmpb)
{
    const int r0 = blockIdx.y * 64, c0 = blockIdx.x * 64;
    const int tid = threadIdx.x, w = tid >> 6, lane = tid & 63;
    const int quad = lane >> 4, l15 = lane & 15;
    const int rowBase = (w >> 1) * 32, colBase = (w & 1) * 32;

    __shared__ __align__(16) ushort_t Als[2][64 * 64];
    __shared__ __align__(16) ushort_t Alc[2][64 * 64];
    __shared__ __align__(16) ushort_t Bls[2][64 * 64];
    __shared__ __align__(16) ushort_t Blc[2][64 * 64];

    const ushort_t* As = sval  + (long)r0 * 512;
    const ushort_t* Ac = cvalb + (long)r0 * 512;
    const ushort_t* Bs = WgsT  + (long)c0 * 512;
    const ushort_t* Bc = WgcT  + (long)c0 * 512;

    f4 acc1[2][2] = {}, acc2[2][2] = {};

    stage_rows64(As, 0, Als[0], w, lane);
    stage_rows64(Ac, 0, Alc[0], w, lane);
    stage_rows64(Bs, 0, Bls[0], w, lane);
    stage_rows64(Bc, 0, Blc[0], w, lane);
    __syncthreads();

    for (int kk = 0; kk < 8; ++kk) {
        const int cur = kk & 1;
        if (kk < 7) {
            const long k0 = (kk + 1) * 64;
            stage_rows64(As, k0, Als[cur ^ 1], w, lane);
            stage_rows64(Ac, k0, Alc[cur ^ 1], w, lane);
            stage_rows64(Bs, k0, Bls[cur ^ 1], w, lane);
            stage_rows64(Bc, k0, Blc[cur ^ 1], w, lane);
        }
#pragma unroll
        for (int ks = 0; ks < 2; ++ks) {
            s8v afs[2], afc[2], bfs[2], bfc[2];
#pragma unroll
            for (int i = 0; i < 2; ++i) {
                int row = rowBase + 16 * i + l15;
                int roff = row * 64 + (((ks * 4 + quad) ^ (row & 7)) * 8);
                afs[i] = *(const s8v*)&Als[cur][roff];
                afc[i] = *(const s8v*)&Alc[cur][roff];
                int col = colBase + 16 * i + l15;
                int coff = col * 64 + (((ks * 4 + quad) ^ (col & 7)) * 8);
                bfs[i] = *(const s8v*)&Bls[cur][coff];
                bfc[i] = *(const s8v*)&Blc[cur][coff];
            }
#pragma unroll
            for (int i = 0; i < 2; ++i)
#pragma unroll
                for (int j = 0; j < 2; ++j) {
                    acc1[i][j] = __builtin_amdgcn_mfma_f32_16x16x32_bf16(afs[i], bfs[j], acc1[i][j], 0, 0, 0);
                    acc2[i][j] = __builtin_amdgcn_mfma_f32_16x16x32_bf16(afc[i], bfc[j], acc2[i][j], 0, 0, 0);
                }
        }
        __syncthreads();
    }

#pragma unroll
    for (int i = 0; i < 2; ++i)
#pragma unroll
        for (int j = 0; j < 2; ++j)
#pragma unroll
            for (int r = 0; r < 4; ++r) {
                int row = r0 + rowBase + 16 * i + quad * 4 + r;
                int col = c0 + colBase + 16 * j + l15;
                long idx = (long)row * 512 + col;
                float g1 = 1.f / (1.f + __expf(-(acc1[i][j][r] + bgs[col])));
                float g2 = 1.f / (1.f + __expf(-(acc2[i][j][r] + bgc[col])));
                tmpb[idx] = f2bf(g1 * bf2f(cvalb[idx]) + g2 * bf2f(sval[idx]));
            }
}

extern "C" void kernel_launch(void* const* d_in, const int* in_sizes, int n_in,
                              void* d_out, int out_size, void* d_ws, size_t ws_size,
                              hipStream_t stream) {
    const float* x      = (const float*)d_in[0];
    const float* y      = (const float*)d_in[1];
    // d_in[2] = attn_x_mask (deterministic tril) -> causal branch
    const float* Wqkv_x = (const float*)d_in[3];
    const float* bqkv_x = (const float*)d_in[4];
    const float* Wqkv_y = (const float*)d_in[5];
    const float* bqkv_y = (const float*)d_in[6];
    const float* Wgs    = (const float*)d_in[7];
    const float* bgs    = (const float*)d_in[8];
    const float* Wgc    = (const float*)d_in[9];
    const float* bgc    = (const float*)d_in[10];
    const float* Wp     = (const float*)d_in[11];
    const float* bp     = (const float*)d_in[12];
    float* out = (float*)d_out;

    // ---- workspace (bf16 shorts), ~46 MB ----
    ushort_t* u = (ushort_t*)d_ws;
    long o = 0;
    ushort_t* xb    = u + o; o += (long)BB * TT * CC;
    ushort_t* yb    = u + o; o += (long)BB * MMM * CC;
    ushort_t* WqxT  = u + o; o += 1536L * 512;
    ushort_t* WqyT  = u + o; o += 1536L * 512;
    ushort_t* WgsT  = u + o; o += 512L * 512;
    ushort_t* WgcT  = u + o; o += 512L * 512;
    ushort_t* WpT   = u + o; o += 512L * 512;
    ushort_t* qkvx  = u + o; o += (long)BB * TT * 1536;
    ushort_t* qkvy  = u + o; o += (long)BB * MMM * 1536;
    ushort_t* vxT   = u + o; o += (long)BB * HH * DD * TT;
    ushort_t* vyT   = u + o; o += (long)BB * HH * DD * MMM;
    ushort_t* kyT   = u + o; o += (long)BB * HH * DD * MMM;
    ushort_t* qyT   = u + o; o += (long)BB * HH * DD * MMM;
    ushort_t* Gt    = u + o; o += 16L * 64 * 64;
    ushort_t* cvalb = u + o; o += (long)BB * TT * CC;
    ushort_t* sval  = u + o; o += (long)BB * TT * CC;
    ushort_t* tmpb  = u + o; o += (long)BB * TT * CC;

    dim3 blk(256);

    // 1) prep: conversions + weight transposes (vectorized)
    prep_k<<<dim3(4864), blk, 0, stream>>>(x, y, Wqkv_x, Wqkv_y, Wgs, Wgc, Wp,
                                           xb, yb, WqxT, WqyT, WgsT, WgcT, WpT);

    // 2) combined qkv projections + fused transpose epilogue (512-thread)
    qkv_k<<<dim3(12, 40), dim3(512), 0, stream>>>(xb, yb, WqxT, WqyT, bqkv_x, bqkv_y,
                                                  qkvx, qkvy, vxT, vyT, kyT, qyT);

    // 3) Gt = SCALE^2 * Q_y^T K_y (8-wave split-M + LDS reduce)
    gt_k<<<dim3(16), dim3(512), 0, stream>>>(qyT, kyT, Gt);

    // 4) fused 3-stream flash (R7/R10 config: best measured)
    flash_fused<<<dim3(32, 16), blk, 0, stream>>>(qkvx, qkvy, Gt, vxT, vyT, cvalb, sval);

    // 5) fused gates + combine (single K pass, both gates per step)
    gate_gemm<<<dim3(8, 64), blk, 0, stream>>>(sval, cvalb, WgsT, WgcT, bgs, bgc, tmpb);

    // 6) out = tmpb @ Wp + bp (fp32, 64x64 tile, 512 blocks, 3-ring pipeline)
    proj_k<<<dim3(8, 64), blk, 0, stream>>>(tmpb, WpT, out, bp);
}

// Round 15
// 193.968 us; speedup vs baseline: 1.0330x; 1.0330x over previous
//
#include <hip/hip_runtime.h>
#include <hip/hip_bf16.h>

typedef unsigned short ushort_t;
typedef __attribute__((ext_vector_type(8))) short s8v;   // 8 bf16 = 4 VGPR (MFMA A/B frag)
typedef __attribute__((ext_vector_type(4))) float f4;    // 4 fp32 acc (MFMA C/D frag)
typedef __attribute__((ext_vector_type(4))) unsigned short u16x4;

// Problem constants: B=2, T=2048, M=512, C=512, H=8, D=64
#define BB 2
#define TT 2048
#define MMM 512
#define CC 512
#define HH 8
#define DD 64
#define SCALE 0.125f
// SCALE * log2(e): folded into q_x so softmax uses bare v_exp_f32 (2^x)
#define SCALE_L2E 0.18033688011112042f

__device__ __forceinline__ ushort_t f2bf(float v) {
    __hip_bfloat16 h = __float2bfloat16(v);
    return *reinterpret_cast<ushort_t*>(&h);
}
__device__ __forceinline__ float bf2f(ushort_t u) {
    __hip_bfloat16 h;
    *reinterpret_cast<ushort_t*>(&h) = u;
    return __bfloat162float(h);
}
// bare 2^x (v_exp_f32). Inputs pre-scaled by log2(e).
__device__ __forceinline__ float exp2_raw(float v) {
    float p;
    asm("v_exp_f32 %0, %1" : "=v"(p) : "v"(v));
    return p;
}

// async global->LDS, 16B per lane. LDS dst = wave-uniform base + lane*16.
__device__ __forceinline__ void gload16(const void* g, void* l) {
    __builtin_amdgcn_global_load_lds((const __attribute__((address_space(1))) void*)g,
                                     (__attribute__((address_space(3))) void*)l, 16, 0, 0);
}

// ---------------------------------------------------------------------------
// prep_k: x/y fp32->bf16 (float4-vectorized) + 5 weight transposes
// (one-pass vectorized, R25).
// ---------------------------------------------------------------------------
__device__ __forceinline__ void transp32(const float* W, ushort_t* WT, int K, int N,
                                         int bx, int by, int tid) {
    const int k0 = by * 32, n0 = bx * 32;
    __shared__ float t[32][33];
    {
        int r = tid >> 3, c = (tid & 7) * 4;
        float4 v = *(const float4*)&W[(long)(k0 + r) * N + n0 + c];
        t[r][c] = v.x; t[r][c + 1] = v.y; t[r][c + 2] = v.z; t[r][c + 3] = v.w;
    }
    __syncthreads();
    {
        int n = tid >> 3, k = (tid & 7) * 4;
        u16x4 o;
        o[0] = f2bf(t[k][n]);     o[1] = f2bf(t[k + 1][n]);
        o[2] = f2bf(t[k + 2][n]); o[3] = f2bf(t[k + 3][n]);
        *(u16x4*)&WT[(long)(n0 + n) * K + k0 + k] = o;
    }
}
__device__ __forceinline__ void cvt4(const float* s, ushort_t* d, long blk, int tid) {
    long i = (blk * 256 + tid) * 4;
    float4 v = *(const float4*)(s + i);
    u16x4 o;
    o[0] = f2bf(v.x); o[1] = f2bf(v.y); o[2] = f2bf(v.z); o[3] = f2bf(v.w);
    *(u16x4*)(d + i) = o;
}

__global__ __launch_bounds__(256) void prep_k(
    const float* __restrict__ x, const float* __restrict__ y,
    const float* __restrict__ Wqx, const float* __restrict__ Wqy,
    const float* __restrict__ Wgs, const float* __restrict__ Wgc,
    const float* __restrict__ Wp,
    ushort_t* __restrict__ xb, ushort_t* __restrict__ yb,
    ushort_t* __restrict__ WqxT, ushort_t* __restrict__ WqyT,
    ushort_t* __restrict__ WgsT, ushort_t* __restrict__ WgcT,
    ushort_t* __restrict__ WpT)
{
    const int bid = blockIdx.x, tid = threadIdx.x;
    if (bid < 2048)      cvt4(x, xb, bid, tid);
    else if (bid < 2560) cvt4(y, yb, bid - 2048, tid);
    else if (bid < 3328) { int l = bid - 2560; transp32(Wqx, WqxT, 512, 1536, l % 48, l / 48, tid); }
    else if (bid < 4096) { int l = bid - 3328; transp32(Wqy, WqyT, 512, 1536, l % 48, l / 48, tid); }
    else if (bid < 4352) { int l = bid - 4096; transp32(Wgs, WgsT, 512, 512, l % 16, l / 16, tid); }
    else if (bid < 4608) { int l = bid - 4352; transp32(Wgc, WgcT, 512, 512, l % 16, l / 16, tid); }
    else                 { int l = bid - 4608; transp32(Wp, WpT, 512, 512, l % 16, l / 16, tid); }
}

// ---------------------------------------------------------------------------
// staging helpers (XOR-swizzled LDS layout, 16B/lane global_load_lds)
// ---------------------------------------------------------------------------
__device__ __forceinline__ void stage_rows128(const ushort_t* src, long k0,
                                              ushort_t* dstL, int w, int lane) {
#pragma unroll
    for (int n = 0; n < 4; ++n) {
        int f = w * 4096 + n * 1024 + lane * 16;
        int row = f >> 7;
        int blk_g = ((f & 127) >> 4) ^ (row & 7);
        gload16(src + (long)row * 512 + k0 + blk_g * 8, dstL + ((w * 4096 + n * 1024) >> 1));
    }
}
__device__ __forceinline__ void stage_rows64(const ushort_t* src, long k0,
                                             ushort_t* dstL, int w, int lane) {
#pragma unroll
    for (int n = 0; n < 2; ++n) {
        int f = w * 2048 + n * 1024 + lane * 16;
        int row = f >> 7;
        int blk_g = ((f & 127) >> 4) ^ (row & 7);
        gload16(src + (long)row * 512 + k0 + blk_g * 8, dstL + ((w * 2048 + n * 1024) >> 1));
    }
}

// ---------------------------------------------------------------------------
// Combined QKV NT GEMM + fused transpose epilogue (R24, 256-thread — the
// measured-best config; R26's 512-thread variant regressed and is reverted).
// ---------------------------------------------------------------------------
__global__ __launch_bounds__(256) void qkv_k(
    const ushort_t* __restrict__ xb, const ushort_t* __restrict__ yb,
    const ushort_t* __restrict__ WqxT, const ushort_t* __restrict__ WqyT,
    const float* __restrict__ bqx, const float* __restrict__ bqy,
    ushort_t* __restrict__ qkvx, ushort_t* __restrict__ qkvy,
    ushort_t* __restrict__ vxT, ushort_t* __restrict__ vyT,
    ushort_t* __restrict__ kyT, ushort_t* __restrict__ qyT)
{
    const int by = blockIdx.y;
    const ushort_t* A; const ushort_t* Bm; const float* bias; ushort_t* O;
    int r0, qcols;
    if (by < 32) { A = xb; Bm = WqxT; bias = bqx; O = qkvx; r0 = by * 128; qcols = 512; }
    else         { A = yb; Bm = WqyT; bias = bqy; O = qkvy; r0 = (by - 32) * 128; qcols = 0; }
    const int c0 = blockIdx.x * 128;
    const int tid = threadIdx.x, w = tid >> 6, lane = tid & 63;
    const int quad = lane >> 4, l15 = lane & 15;
    const int rowBase = (w >> 1) * 64, colBase = (w & 1) * 64;

    // single shared pool: [0,8192)=Al0 [8192,16384)=Al1 [16384,24576)=Bl0
    // [24576,32768)=Bl1; epilogue transpose scratch t[128][136] aliases [0,17408).
    __shared__ __align__(16) ushort_t sh[32768];

    const ushort_t* Ab = A + (long)r0 * 512;
    const ushort_t* Bb = Bm + (long)c0 * 512;

    f4 acc[4][4] = {};

    stage_rows128(Ab, 0, sh, w, lane);
    stage_rows128(Bb, 0, sh + 16384, w, lane);
    __syncthreads();

    for (int kk = 0; kk < 8; ++kk) {
        const int cur = kk & 1;
        ushort_t* AlCur = sh + cur * 8192;
        ushort_t* BlCur = sh + 16384 + cur * 8192;
        if (kk < 7) {
            stage_rows128(Ab, (kk + 1) * 64, sh + (cur ^ 1) * 8192, w, lane);
            stage_rows128(Bb, (kk + 1) * 64, sh + 16384 + (cur ^ 1) * 8192, w, lane);
        }
#pragma unroll
        for (int ks = 0; ks < 2; ++ks) {
            s8v af[4], bfr[4];
#pragma unroll
            for (int i = 0; i < 4; ++i) {
                int row = rowBase + 16 * i + l15;
                af[i] = *(const s8v*)&AlCur[row * 64 + (((ks * 4 + quad) ^ (row & 7)) * 8)];
                int col = colBase + 16 * i + l15;
                bfr[i] = *(const s8v*)&BlCur[col * 64 + (((ks * 4 + quad) ^ (col & 7)) * 8)];
            }
#pragma unroll
            for (int i = 0; i < 4; ++i)
#pragma unroll
                for (int j = 0; j < 4; ++j)
                    acc[i][j] = __builtin_amdgcn_mfma_f32_16x16x32_bf16(af[i], bfr[j], acc[i][j], 0, 0, 0);
        }
        __syncthreads();
    }

    // transpose destination select (block-uniform)
    ushort_t* dstT = nullptr; long zb = 0; int S = 0, srow0 = 0, h0 = 0;
    if (by < 32) {
        if (c0 >= 1024) {
            dstT = vxT; S = TT; zb = (long)(r0 >> 11) * 8;
            h0 = (c0 - 1024) >> 6; srow0 = r0 & 2047;
        }
    } else {
        const int slice = c0 >> 9;   // 0:q 1:k 2:v of y
        dstT = (slice == 0) ? qyT : (slice == 1) ? kyT : vyT;
        S = MMM; zb = (long)(r0 >> 9) * 8;
        h0 = (c0 & 511) >> 6; srow0 = r0 & 511;
    }

    // epilogue: normal O write + (optional) LDS scratch write for transpose
#pragma unroll
    for (int i = 0; i < 4; ++i)
#pragma unroll
        for (int j = 0; j < 4; ++j)
#pragma unroll
            for (int r = 0; r < 4; ++r) {
                int lrow = rowBase + 16 * i + quad * 4 + r;
                int lcol = colBase + 16 * j + l15;
                int col = c0 + lcol;
                float v = acc[i][j][r] + bias[col];
                if (col < qcols) v *= SCALE_L2E;   // fold SCALE*log2e into q_x
                ushort_t bv = f2bf(v);
                O[(long)(r0 + lrow) * 1536 + col] = bv;
                if (dstT) sh[lrow * 136 + (lcol ^ (((lrow >> 3) & 7) * 8))] = bv;
            }

    if (dstT) {
        __syncthreads();
        // 2048 tasks: (d128, s-chunk). 16 consecutive threads share d128 ->
        // 16 x 16B contiguous global stores (coalesced 256B).
#pragma unroll
        for (int p = 0; p < 8; ++p) {
            int task = p * 256 + tid;
            int d128 = task >> 4, sc = task & 15;
            s8v o;
#pragma unroll
            for (int k = 0; k < 8; ++k)
                o[k] = (short)sh[(sc * 8 + k) * 136 + (d128 ^ ((sc & 7) * 8))];
            int h = h0 + (d128 >> 6), d = d128 & 63;
            long addr = ((zb + h) * 64 + d) * (long)S + srow0 + sc * 8;
            *(s8v*)&dstT[addr] = o;
        }
    }
}

// ---------------------------------------------------------------------------
// Proj NT GEMM. 64x64 tile (grid 8x64 = 512 blocks -> 2 blocks/CU),
// 3-slot ring + counted vmcnt single-barrier pipeline.
// ---------------------------------------------------------------------------
__global__ __launch_bounds__(256) void proj_k(
    const ushort_t* __restrict__ A, const ushort_t* __restrict__ Bm,
    float* __restrict__ O, const float* __restrict__ bias)
{
    const int r0 = blockIdx.y * 64, c0 = blockIdx.x * 64;
    const int tid = threadIdx.x, w = tid >> 6, lane = tid & 63;
    const int quad = lane >> 4, l15 = lane & 15;
    const int rowBase = (w >> 1) * 32, colBase = (w & 1) * 32;

    __shared__ __align__(16) ushort_t Al[3][64 * 64];
    __shared__ __align__(16) ushort_t Bl[3][64 * 64];

    const ushort_t* Ab = A + (long)r0 * 512;
    const ushort_t* Bb = Bm + (long)c0 * 512;

    f4 acc[2][2] = {};

    stage_rows64(Ab, 0, Al[0], w, lane);
    stage_rows64(Bb, 0, Bl[0], w, lane);
    stage_rows64(Ab, 64, Al[1], w, lane);
    stage_rows64(Bb, 64, Bl[1], w, lane);

    int cur = 0;
    for (int kk = 0; kk < 8; ++kk) {
        if (kk + 1 < 8) asm volatile("s_waitcnt vmcnt(4)" ::: "memory");
        else            asm volatile("s_waitcnt vmcnt(0)" ::: "memory");
        asm volatile("s_barrier" ::: "memory");
        if (kk + 2 < 8) {
            int s = cur + 2; if (s >= 3) s -= 3;
            stage_rows64(Ab, (kk + 2) * 64, Al[s], w, lane);
            stage_rows64(Bb, (kk + 2) * 64, Bl[s], w, lane);
        }
#pragma unroll
        for (int ks = 0; ks < 2; ++ks) {
            s8v af[2], bfr[2];
#pragma unroll
            for (int i = 0; i < 2; ++i) {
                int row = rowBase + 16 * i + l15;
                af[i] = *(const s8v*)&Al[cur][row * 64 + (((ks * 4 + quad) ^ (row & 7)) * 8)];
                int col = colBase + 16 * i + l15;
                bfr[i] = *(const s8v*)&Bl[cur][col * 64 + (((ks * 4 + quad) ^ (col & 7)) * 8)];
            }
#pragma unroll
            for (int i = 0; i < 2; ++i)
#pragma unroll
                for (int j = 0; j < 2; ++j)
                    acc[i][j] = __builtin_amdgcn_mfma_f32_16x16x32_bf16(af[i], bfr[j], acc[i][j], 0, 0, 0);
        }
        if (++cur == 3) cur = 0;
    }

#pragma unroll
    for (int i = 0; i < 2; ++i)
#pragma unroll
        for (int j = 0; j < 2; ++j)
#pragma unroll
            for (int r = 0; r < 4; ++r) {
                int row = r0 + rowBase + 16 * i + quad * 4 + r;
                int col = c0 + colBase + 16 * j + l15;
                O[(long)row * 512 + col] = acc[i][j][r] + bias[col];
            }
}

// ---------------------------------------------------------------------------
// Gt[z][d2][d1] = SCALE^2 * sum_m q_y[m,d2]*k_y[m,d1]  (8-wave split-M, R25).
// ---------------------------------------------------------------------------
__global__ __launch_bounds__(512) void gt_k(const ushort_t* __restrict__ qyT,
                                            const ushort_t* __restrict__ kyT,
                                            ushort_t* __restrict__ Gt)
{
    const int z = blockIdx.x;
    const int tid = threadIdx.x, w = tid >> 6, lane = tid & 63;
    const int quad = lane >> 4, l15 = lane & 15;
    const ushort_t* A  = qyT + (long)z * 64 * MMM;
    const ushort_t* Bm = kyT + (long)z * 64 * MMM;
    __shared__ float red[8][4096];
    f4 acc[4][4] = {};
#pragma unroll
    for (int kk = 0; kk < 2; ++kk) {
        const int ks = w * 2 + kk;
        s8v af[4], bfr[4];
#pragma unroll
        for (int i = 0; i < 4; ++i) {
            af[i]  = *(const s8v*)(A  + (long)(16 * i + l15) * MMM + ks * 32 + quad * 8);
            bfr[i] = *(const s8v*)(Bm + (long)(16 * i + l15) * MMM + ks * 32 + quad * 8);
        }
#pragma unroll
        for (int i = 0; i < 4; ++i)
#pragma unroll
            for (int j = 0; j < 4; ++j)
                acc[i][j] = __builtin_amdgcn_mfma_f32_16x16x32_bf16(af[i], bfr[j], acc[i][j], 0, 0, 0);
    }
#pragma unroll
    for (int i = 0; i < 4; ++i)
#pragma unroll
        for (int j = 0; j < 4; ++j)
            *(f4*)&red[w][(i * 4 + j) * 256 + lane * 4] = acc[i][j];
    __syncthreads();
    const float s2 = SCALE * SCALE;
    const int iw = w & 3, j0 = (w >> 2) * 2;
#pragma unroll
    for (int jj = 0; jj < 2; ++jj) {
        const int j = j0 + jj;
        f4 s = *(const f4*)&red[0][(iw * 4 + j) * 256 + lane * 4];
#pragma unroll
        for (int ww = 1; ww < 8; ++ww)
            s += *(const f4*)&red[ww][(iw * 4 + j) * 256 + lane * 4];
#pragma unroll
        for (int r = 0; r < 4; ++r) {
            int d2 = 16 * iw + quad * 4 + r, d1 = 16 * j + l15;
            Gt[(long)z * 4096 + d2 * 64 + d1] = f2bf(s2 * s[r]);
        }
    }
}

// ---------------------------------------------------------------------------
// Fused 3-stream flash — R7/R10/R13 config (measured best: 58.3-59.9us).
// ---------------------------------------------------------------------------
__device__ __forceinline__ void stage_k64(const ushort_t* src, long rstride, int s0,
                                          ushort_t* Kl, int w, int lane) {
#pragma unroll
    for (int n = 0; n < 2; ++n) {
        int f = w * 2048 + n * 1024 + lane * 16;
        int row = f >> 7;
        int krow = ((row & 15) << 2) | (row >> 4);   // k-interleave permutation
        int blk = ((f & 127) >> 4) ^ (row & 7);
        gload16(src + (long)(s0 + krow) * rstride + blk * 8, &Kl[(w * 2048 + n * 1024) >> 1]);
    }
}
__device__ __forceinline__ void stage_v64(const ushort_t* src, long rstride, int s0,
                                          ushort_t* Vl, int w, int lane) {
#pragma unroll
    for (int n = 0; n < 2; ++n) {
        int f = w * 2048 + n * 1024 + lane * 16;
        int row = f >> 7;
        int blk = ((f & 127) >> 4) ^ (row & 7);
        gload16(src + (long)row * rstride + s0 + blk * 8, &Vl[(w * 2048 + n * 1024) >> 1]);
    }
}
__device__ __forceinline__ void qk8(f4 Sc[4], const s8v qf[2], const ushort_t* Kl,
                                    int quad, int l15) {
    __builtin_amdgcn_s_setprio(1);
#pragma unroll
    for (int ks = 0; ks < 2; ++ks)
#pragma unroll
        for (int c = 0; c < 4; ++c) {
            int row = 16 * c + l15;
            s8v bb = *(const s8v*)&Kl[row * 64 + (((ks * 4 + quad) ^ (row & 7)) * 8)];
            Sc[c] = __builtin_amdgcn_mfma_f32_16x16x32_bf16(qf[ks], bb, Sc[c], 0, 0, 0);
        }
    __builtin_amdgcn_s_setprio(0);
}
__device__ __forceinline__ void qk8_dual(f4 Ss[4], f4 Sp[4], const s8v qa[2], const s8v qb[2],
                                         const ushort_t* Kl, int quad, int l15) {
    __builtin_amdgcn_s_setprio(1);
#pragma unroll
    for (int ks = 0; ks < 2; ++ks)
#pragma unroll
        for (int c = 0; c < 4; ++c) {
            int row = 16 * c + l15;
            s8v bb = *(const s8v*)&Kl[row * 64 + (((ks * 4 + quad) ^ (row & 7)) * 8)];
            Ss[c] = __builtin_amdgcn_mfma_f32_16x16x32_bf16(qa[ks], bb, Ss[c], 0, 0, 0);
            Sp[c] = __builtin_amdgcn_mfma_f32_16x16x32_bf16(qb[ks], bb, Sp[c], 0, 0, 0);
        }
    __builtin_amdgcn_s_setprio(0);
}
// preload the 8 V fragments of this tile into registers (issued before smax
// so the ds_read latency overlaps the softmax VALU chain)
__device__ __forceinline__ void vload8(s8v vf[8], const ushort_t* Vl, int quad, int l15) {
#pragma unroll
    for (int ks = 0; ks < 2; ++ks)
#pragma unroll
        for (int c = 0; c < 4; ++c) {
            int row = 16 * c + l15;
            vf[ks * 4 + c] = *(const s8v*)&Vl[row * 64 + (((ks * 4 + quad) ^ (row & 7)) * 8)];
        }
}
// fixed-max softmax: p = 2^v (logits pre-scaled by log2e); lane-local l;
// P written as packed b64 (k-cols 4*l15..4*l15+3 consecutive after interleave)
__device__ __forceinline__ void smax0(const f4 Sc[4], float l_i[4], ushort_t* PlW,
                                      int diag, int trow0, int s0, int quad, int l15) {
#pragma unroll
    for (int r = 0; r < 4; ++r) {
        const int trow = trow0 + quad * 4 + r;
        u16x4 o;
#pragma unroll
        for (int c = 0; c < 4; ++c) {
            float v = Sc[c][r];
            if (diag && (s0 + 4 * l15 + c) > trow) v = -3e38f;
            float p = exp2_raw(v);
            l_i[r] += p;
            o[c] = f2bf(p);
        }
        *(u16x4*)&PlW[(quad * 4 + r) * 72 + 4 * l15] = o;
    }
}
// PV consuming register V-frags (P still via per-wave LDS)
__device__ __forceinline__ void pv8r(f4 Oc[4], const ushort_t* PlW, const s8v vf[8],
                                     int quad, int l15) {
    __builtin_amdgcn_s_setprio(1);
#pragma unroll
    for (int ks = 0; ks < 2; ++ks) {
        s8v a = *(const s8v*)&PlW[l15 * 72 + ks * 32 + quad * 8];
#pragma unroll
        for (int c = 0; c < 4; ++c)
            Oc[c] = __builtin_amdgcn_mfma_f32_16x16x32_bf16(a, vf[ks * 4 + c], Oc[c], 0, 0, 0);
    }
    __builtin_amdgcn_s_setprio(0);
}
__device__ __forceinline__ void pv8r_dual(f4 Os[4], f4 Op[4], const ushort_t* Ps,
                                          const ushort_t* Pp, const s8v vf[8],
                                          int quad, int l15) {
    __builtin_amdgcn_s_setprio(1);
#pragma unroll
    for (int ks = 0; ks < 2; ++ks) {
        s8v as = *(const s8v*)&Ps[l15 * 72 + ks * 32 + quad * 8];
        s8v ap = *(const s8v*)&Pp[l15 * 72 + ks * 32 + quad * 8];
#pragma unroll
        for (int c = 0; c < 4; ++c) {
            Os[c] = __builtin_amdgcn_mfma_f32_16x16x32_bf16(as, vf[ks * 4 + c], Os[c], 0, 0, 0);
            Op[c] = __builtin_amdgcn_mfma_f32_16x16x32_bf16(ap, vf[ks * 4 + c], Op[c], 0, 0, 0);
        }
    }
    __builtin_amdgcn_s_setprio(0);
}

__global__ __launch_bounds__(256, 2) void flash_fused(
    const ushort_t* __restrict__ qkvx, const ushort_t* __restrict__ qkvy,
    const ushort_t* __restrict__ Gt, const ushort_t* __restrict__ vxT,
    const ushort_t* __restrict__ vyT,
    ushort_t* __restrict__ cval, ushort_t* __restrict__ sval)
{
    const int z = blockIdx.y, b = z >> 3, h = z & 7;
    const ushort_t* qx = qkvx + (long)b * (TT * 1536) + h * 64;   // pre-scaled SCALE*log2e
    const ushort_t* kx = qx + 512;
    const ushort_t* ky = qkvy + (long)b * (MMM * 1536) + 512 + h * 64;
    const ushort_t* Gz = Gt + (long)z * 4096;
    const ushort_t* vx = vxT + (long)z * (64 * TT);
    const ushort_t* vy = vyT + (long)z * (64 * MMM);

    // load-balance: z<8 long-first, z>=8 short-first (R2's best-measured pairing)
    const int xw = (z & 8) ? (int)blockIdx.x : (int)(gridDim.x - 1 - blockIdx.x);
    const int t0 = xw * 64;
    const int tid = threadIdx.x, w = tid >> 6, lane = tid & 63;
    const int quad = lane >> 4, l15 = lane & 15;

    __shared__ __align__(16) ushort_t Kl[2][64 * 64];
    __shared__ __align__(16) ushort_t Vl[2][64 * 64];
    __shared__ __align__(16) ushort_t Pl[2][4 * 16 * 72];   // [stream][wave P]
    ushort_t* PlWs = &Pl[0][w * 1152];
    ushort_t* PlWp = &Pl[1][w * 1152];

    // prefetch tile 0 (cross) early
    stage_k64(ky, 1536, 0, Kl[0], w, lane);
    stage_v64(vy, MMM, 0, Vl[0], w, lane);

    // Q frags + q~ = qx_scaled @ Gt^T (permuted Gt rows -> packed P writes).
    const int qrow = t0 + 16 * w + l15;
    s8v qfx[2], qft[2];
    qfx[0] = *(const s8v*)(qx + (long)qrow * 1536 + quad * 8);
    qfx[1] = *(const s8v*)(qx + (long)qrow * 1536 + 32 + quad * 8);
    {
        f4 qa[4] = {};
#pragma unroll
        for (int ks = 0; ks < 2; ++ks)
#pragma unroll
            for (int j = 0; j < 4; ++j) {
                s8v bb = *(const s8v*)(Gz + (4 * l15 + j) * 64 + ks * 32 + quad * 8);
                qa[j] = __builtin_amdgcn_mfma_f32_16x16x32_bf16(qfx[ks], bb, qa[j], 0, 0, 0);
            }
#pragma unroll
        for (int r = 0; r < 4; ++r) {
            u16x4 o;
#pragma unroll
            for (int j = 0; j < 4; ++j) o[j] = f2bf(qa[j][r]);
            *(u16x4*)&PlWs[(quad * 4 + r) * 72 + 4 * l15] = o;
        }
        qft[0] = *(const s8v*)&PlWs[l15 * 72 + quad * 8];
        qft[1] = *(const s8v*)&PlWs[l15 * 72 + 32 + quad * 8];
    }

    f4 Occ[4] = {}, Ocs[4] = {}, Ocp[4] = {};
    float lc[4] = {}, ls[4] = {}, lp[4] = {};

    const int nT1 = MMM / 64;                 // 8 cross tiles
    const int nTiles = nT1 + t0 / 64 + 1;

    for (int ti = 0; ti < nTiles; ++ti) {
        const int bi = ti & 1;
        __syncthreads();   // drains cur-buf loads
        if (ti + 1 < nTiles) {
            const int tn = ti + 1, bn = tn & 1;
            if (tn < nT1) {
                stage_k64(ky, 1536, tn * 64, Kl[bn], w, lane);
                stage_v64(vy, MMM, tn * 64, Vl[bn], w, lane);
            } else {
                const int s0n = (tn - nT1) * 64;
                stage_k64(kx, 1536, s0n, Kl[bn], w, lane);
                stage_v64(vx, TT, s0n, Vl[bn], w, lane);
            }
        }
        if (ti < nT1) {
            // ---- cross: qk -> vload (overlaps smax) -> smax -> pv(regs) ----
            f4 Sc[4] = {};
            qk8(Sc, qfx, Kl[bi], quad, l15);
            s8v vf[8];
            vload8(vf, Vl[bi], quad, l15);
            smax0(Sc, lc, PlWs, 0, 0, 0, quad, l15);
            pv8r(Occ, PlWs, vf, quad, l15);
        } else {
            // ---- causal: dual-stream with shared K/V frags ----
            const int s0 = (ti - nT1) * 64;
            const int diag = (s0 == t0);
            f4 Ss[4] = {}, Sp[4] = {};
            qk8_dual(Ss, Sp, qfx, qft, Kl[bi], quad, l15);
            s8v vf[8];
            vload8(vf, Vl[bi], quad, l15);
            smax0(Ss, ls, PlWs, diag, t0 + 16 * w, s0, quad, l15);
            smax0(Sp, lp, PlWp, diag, t0 + 16 * w, s0, quad, l15);
            pv8r_dual(Ocs, Ocp, PlWs, PlWp, vf, quad, l15);
        }
    }

    // reduce l over the 16 lanes of each quad-group (cols of the row)
#pragma unroll
    for (int r = 0; r < 4; ++r)
#pragma unroll
        for (int mb = 1; mb < 16; mb <<= 1) {
            lc[r] += __shfl_xor(lc[r], mb, 64);
            ls[r] += __shfl_xor(ls[r], mb, 64);
            lp[r] += __shfl_xor(lp[r], mb, 64);
        }

    const long ob = (long)b * (TT * CC) + h * 64;
#pragma unroll
    for (int r = 0; r < 4; ++r) {
        int row = t0 + 16 * w + quad * 4 + r;
        float ic = 1.f / lc[r], ip = 1.f / lp[r], isv = 1.f / ls[r];
#pragma unroll
        for (int c = 0; c < 4; ++c) {
            long idx = ob + (long)row * CC + 16 * c + l15;
            cval[idx] = f2bf(Occ[c][r] * ic + Ocp[c][r] * ip);
            sval[idx] = f2bf(Ocs[c][r] * isv);
        }
    }
}

// ---------------------------------------------------------------------------
// Fused gate: SINGLE pass over K — both gate GEMMs per k-step (R10, −4us).
// ---------------------------------------------------------------------------
__global__ __launch_bounds__(256) void gate_gemm(
    const ushort_t* __restrict__ sval, const ushort_t* __restrict__ cvalb,
    const ushort_t* __restrict__ WgsT, const ushort_t* __restrict__ WgcT,
    const float* __restrict__ bgs, const float* __restrict__ bgc,
    ushort_t* __restrict__ tmpb)
{
    const int r0 = blockIdx.y * 64, c0 = blockIdx.x * 64;
    const int tid = threadIdx.x, w = tid >> 6, lane = tid & 63;
    const int quad = lane >> 4, l15 = lane & 15;
    const int rowBase = (w >> 1) * 32, colBase = (w & 1) * 32;

    __shared__ __align__(16) ushort_t Als[2][64 * 64];
    __shared__ __align__(16) ushort_t Alc[2][64 * 64];
    __shared__ __align__(16) ushort_t Bls[2][64 * 64];
    __shared__ __align__(16) ushort_t Blc[2][64 * 64];

    const ushort_t* As = sval  + (long)r0 * 512;
    const ushort_t* Ac = cvalb + (long)r0 * 512;
    const ushort_t* Bs = WgsT  + (long)c0 * 512;
    const ushort_t* Bc = WgcT  + (long)c0 * 512;

    f4 acc1[2][2] = {}, acc2[2][2] = {};

    stage_rows64(As, 0, Als[0], w, lane);
    stage_rows64(Ac, 0, Alc[0], w, lane);
    stage_rows64(Bs, 0, Bls[0], w, lane);
    stage_rows64(Bc, 0, Blc[0], w, lane);
    __syncthreads();

    for (int kk = 0; kk < 8; ++kk) {
        const int cur = kk & 1;
        if (kk < 7) {
            const long k0 = (kk + 1) * 64;
            stage_rows64(As, k0, Als[cur ^ 1], w, lane);
            stage_rows64(Ac, k0, Alc[cur ^ 1], w, lane);
            stage_rows64(Bs, k0, Bls[cur ^ 1], w, lane);
            stage_rows64(Bc, k0, Blc[cur ^ 1], w, lane);
        }
#pragma unroll
        for (int ks = 0; ks < 2; ++ks) {
            s8v afs[2], afc[2], bfs[2], bfc[2];
#pragma unroll
            for (int i = 0; i < 2; ++i) {
                int row = rowBase + 16 * i + l15;
                int roff = row * 64 + (((ks * 4 + quad) ^ (row & 7)) * 8);
                afs[i] = *(const s8v*)&Als[cur][roff];
                afc[i] = *(const s8v*)&Alc[cur][roff];
                int col = colBase + 16 * i + l15;
                int coff = col * 64 + (((ks * 4 + quad) ^ (col & 7)) * 8);
                bfs[i] = *(const s8v*)&Bls[cur][coff];
                bfc[i] = *(const s8v*)&Blc[cur][coff];
            }
#pragma unroll
            for (int i = 0; i < 2; ++i)
#pragma unroll
                for (int j = 0; j < 2; ++j) {
                    acc1[i][j] = __builtin_amdgcn_mfma_f32_16x16x32_bf16(afs[i], bfs[j], acc1[i][j], 0, 0, 0);
                    acc2[i][j] = __builtin_amdgcn_mfma_f32_16x16x32_bf16(afc[i], bfc[j], acc2[i][j], 0, 0, 0);
                }
        }
        __syncthreads();
    }

#pragma unroll
    for (int i = 0; i < 2; ++i)
#pragma unroll
        for (int j = 0; j < 2; ++j)
#pragma unroll
            for (int r = 0; r < 4; ++r) {
                int row = r0 + rowBase + 16 * i + quad * 4 + r;
                int col = c0 + colBase + 16 * j + l15;
                long idx = (long)row * 512 + col;
                float g1 = 1.f / (1.f + __expf(-(acc1[i][j][r] + bgs[col])));
                float g2 = 1.f / (1.f + __expf(-(acc2[i][j][r] + bgc[col])));
                tmpb[idx] = f2bf(g1 * bf2f(cvalb[idx]) + g2 * bf2f(sval[idx]));
            }
}

extern "C" void kernel_launch(void* const* d_in, const int* in_sizes, int n_in,
                              void* d_out, int out_size, void* d_ws, size_t ws_size,
                              hipStream_t stream) {
    const float* x      = (const float*)d_in[0];
    const float* y      = (const float*)d_in[1];
    // d_in[2] = attn_x_mask (deterministic tril) -> causal branch
    const float* Wqkv_x = (const float*)d_in[3];
    const float* bqkv_x = (const float*)d_in[4];
    const float* Wqkv_y = (const float*)d_in[5];
    const float* bqkv_y = (const float*)d_in[6];
    const float* Wgs    = (const float*)d_in[7];
    const float* bgs    = (const float*)d_in[8];
    const float* Wgc    = (const float*)d_in[9];
    const float* bgc    = (const float*)d_in[10];
    const float* Wp     = (const float*)d_in[11];
    const float* bp     = (const float*)d_in[12];
    float* out = (float*)d_out;

    // ---- workspace (bf16 shorts), ~46 MB ----
    ushort_t* u = (ushort_t*)d_ws;
    long o = 0;
    ushort_t* xb    = u + o; o += (long)BB * TT * CC;
    ushort_t* yb    = u + o; o += (long)BB * MMM * CC;
    ushort_t* WqxT  = u + o; o += 1536L * 512;
    ushort_t* WqyT  = u + o; o += 1536L * 512;
    ushort_t* WgsT  = u + o; o += 512L * 512;
    ushort_t* WgcT  = u + o; o += 512L * 512;
    ushort_t* WpT   = u + o; o += 512L * 512;
    ushort_t* qkvx  = u + o; o += (long)BB * TT * 1536;
    ushort_t* qkvy  = u + o; o += (long)BB * MMM * 1536;
    ushort_t* vxT   = u + o; o += (long)BB * HH * DD * TT;
    ushort_t* vyT   = u + o; o += (long)BB * HH * DD * MMM;
    ushort_t* kyT   = u + o; o += (long)BB * HH * DD * MMM;
    ushort_t* qyT   = u + o; o += (long)BB * HH * DD * MMM;
    ushort_t* Gt    = u + o; o += 16L * 64 * 64;
    ushort_t* cvalb = u + o; o += (long)BB * TT * CC;
    ushort_t* sval  = u + o; o += (long)BB * TT * CC;
    ushort_t* tmpb  = u + o; o += (long)BB * TT * CC;

    dim3 blk(256);

    // 1) prep: conversions + weight transposes (vectorized)
    prep_k<<<dim3(4864), blk, 0, stream>>>(x, y, Wqkv_x, Wqkv_y, Wgs, Wgc, Wp,
                                           xb, yb, WqxT, WqyT, WgsT, WgcT, WpT);

    // 2) combined qkv projections + fused transpose epilogue (256-thread)
    qkv_k<<<dim3(12, 40), blk, 0, stream>>>(xb, yb, WqxT, WqyT, bqkv_x, bqkv_y,
                                            qkvx, qkvy, vxT, vyT, kyT, qyT);

    // 3) Gt = SCALE^2 * Q_y^T K_y (8-wave split-M + LDS reduce)
    gt_k<<<dim3(16), dim3(512), 0, stream>>>(qyT, kyT, Gt);

    // 4) fused 3-stream flash (R7/R10/R13 config: best measured)
    flash_fused<<<dim3(32, 16), blk, 0, stream>>>(qkvx, qkvy, Gt, vxT, vyT, cvalb, sval);

    // 5) fused gates + combine (single K pass, both gates per step)
    gate_gemm<<<dim3(8, 64), blk, 0, stream>>>(sval, cvalb, WgsT, WgcT, bgs, bgc, tmpb);

    // 6) out = tmpb @ Wp + bp (fp32, 64x64 tile, 512 blocks, 3-ring pipeline)
    proj_k<<<dim3(8, 64), blk, 0, stream>>>(tmpb, WpT, out, bp);
}